// Round 14
// baseline (110.887 us; speedup 1.0000x reference)
//
#include <hip/hip_runtime.h>
#include <hip/hip_bf16.h>

#define TT 128
#define DD 64
#define BHN 32
#define SCALE 0.125f
#define NEGF -1000000.0f

// float-element offsets into d_out (concatenated return order: z, pre, vg, M, L)
#define OFF_Z   ((size_t)0)
#define OFF_PRE ((size_t)(BHN*TT*DD))                       // 262144
#define OFF_VG  (OFF_PRE + (size_t)BHN*TT*TT*TT)            // 67371008
#define OFF_M   (OFF_VG + (size_t)BHN*TT*TT*DD)             // 100925440
#define OFF_L   (OFF_M + (size_t)(BHN*TT))                  // 100929536

// workspace layout (short elements): pre-swizzled bf16 images, 2.5 MB total
#define WS_K2   ((size_t)0)           // [bn][8192] K2[k][h] bf16, XOR-swizzled
#define WS_G2T  ((size_t)262144)      // [bn][8192] G2T[h][k] bf16, XOR-swizzled
#define WS_Q    ((size_t)524288)      // [bn][8192] Q[q][h]  bf16, XOR-swizzled
#define WS_G1   ((size_t)786432)      // [bn][8192] silu(v1)[j][h] bf16, plain
#define WS_K1   ((size_t)1048576)     // [bn][8192] K1[j][h] bf16, XOR-swizzled

typedef __attribute__((ext_vector_type(8))) short short8b;   // 8 bf16 (4 VGPRs)
typedef __attribute__((ext_vector_type(4))) short short4b;
typedef __attribute__((ext_vector_type(4))) float f32x4;

__device__ __forceinline__ short f2bf(float f) {
    __hip_bfloat16 h = __float2bfloat16(f);
    return *reinterpret_cast<short*>(&h);
}
__device__ __forceinline__ float bf2f(short s) {
    union { unsigned u; float f; } v; v.u = ((unsigned)(unsigned short)s) << 16;
    return v.f;
}

// async copy of the first nchunks KB of a 16KB linear image -> LDS (linear).
// chunk c handled by wave c%4; lane l moves 16B.
__device__ __forceinline__ void async_copy_chunks(const short* __restrict__ src, short* dst,
                                                  int tid, int nchunks) {
    const int w    = tid >> 6;
    const int lane = tid & 63;
    const char* s = (const char*)src + lane * 16;
    char* d = (char*)dst;
#pragma unroll
    for (int i = 0; i < 4; i++) {
        const int c = (i << 2) + w;
        if (c < nchunks)
            __builtin_amdgcn_global_load_lds(
                (const __attribute__((address_space(1))) void*)(s + c * 1024),
                (__attribute__((address_space(3))) void*)(d + c * 1024), 16, 0, 0);
    }
}
__device__ __forceinline__ void async_copy16k(const short* __restrict__ src, short* dst, int tid) {
    async_copy_chunks(src, dst, tid, 16);
}

// ---------------- prep: once-per-(b,n) conversions into d_ws ----------------
__global__ __launch_bounds__(256) void k_prep(const float* __restrict__ q,
                                              const float* __restrict__ k1,
                                              const float* __restrict__ k2,
                                              const float* __restrict__ v1,
                                              const float* __restrict__ v2,
                                              short* __restrict__ ws) {
    const int bid   = blockIdx.x;     // 256 = 32 bn x 8 slices
    const int bn    = bid >> 3;
    const int slice = bid & 7;
    const int tid   = threadIdx.x;
    const int e4 = slice * 256 + tid; // 0..2047
    const int e  = e4 * 4;
    const int r  = e >> 6;
    const int h  = e & 63;
    const size_t g = (size_t)bn * TT * DD + e;

    short* wsK2  = ws + WS_K2  + (size_t)bn * 8192;
    short* wsG2T = ws + WS_G2T + (size_t)bn * 8192;
    short* wsQ   = ws + WS_Q   + (size_t)bn * 8192;
    short* wsG1  = ws + WS_G1  + (size_t)bn * 8192;
    short* wsK1  = ws + WS_K1  + (size_t)bn * 8192;

    const f32x4 k2v = *(const f32x4*)(k2 + g);
    const f32x4 k1v = *(const f32x4*)(k1 + g);
    const f32x4 qv  = *(const f32x4*)(q  + g);
    const f32x4 v2v = *(const f32x4*)(v2 + g);
    const f32x4 v1v = *(const f32x4*)(v1 + g);

    short4b kb, ab, qb, gb;
    kb[0] = f2bf(k2v.x); kb[1] = f2bf(k2v.y); kb[2] = f2bf(k2v.z); kb[3] = f2bf(k2v.w);
    ab[0] = f2bf(k1v.x); ab[1] = f2bf(k1v.y); ab[2] = f2bf(k1v.z); ab[3] = f2bf(k1v.w);
    qb[0] = f2bf(qv.x);  qb[1] = f2bf(qv.y);  qb[2] = f2bf(qv.z);  qb[3] = f2bf(qv.w);
#pragma unroll
    for (int i = 0; i < 4; i++) {
        float x = v1v[i];
        gb[i] = f2bf(x / (1.f + __expf(-x)));
    }
    const int idx = e ^ ((r & 7) << 3);
    *(short4b*)&wsK2[idx] = kb;
    *(short4b*)&wsK1[idx] = ab;
    *(short4b*)&wsQ[idx]  = qb;
    *(short4b*)&wsG1[e]   = gb;
    wsG2T[((h + 0) * TT + r) ^ (((h + 0) & 7) << 3)] = f2bf(v2v.x);
    wsG2T[((h + 1) * TT + r) ^ (((h + 1) & 7) << 3)] = f2bf(v2v.y);
    wsG2T[((h + 2) * TT + r) ^ (((h + 2) & 7) << 3)] = f2bf(v2v.z);
    wsG2T[((h + 3) * TT + r) ^ (((h + 3) & 7) << 3)] = f2bf(v2v.w);
}

// ---- role bodies (inlined into the fused kernel; smem is the 50KB union) ----

__device__ __forceinline__ void do_vg(int sub, const float* __restrict__ v1,
                                      const float* __restrict__ v2,
                                      float* __restrict__ out, char* smem) {
    const int bn  = sub >> 7;
    const int p   = sub & 127;
    const int tid = threadIdx.x;
    float* g1 = (float*)smem;              // [64]
    if (tid < DD) {
        float x = v1[(size_t)(bn*TT + p)*DD + tid];
        g1[tid] = x / (1.0f + __expf(-x));
    }
    __syncthreads();
    const f32x4* v2f = (const f32x4*)(v2 + (size_t)bn*TT*DD);
    float* dst = out + OFF_VG + (size_t)sub*TT*DD;
    const f32x4* g14 = (const f32x4*)g1;
    for (int i = tid; i < TT*DD/4; i += 256) {
        int h4 = i & 15;
        f32x4 v = v2f[i];
        f32x4 g = g14[h4];
        f32x4 r = v * g;
        ((f32x4*)dst)[i] = r;              // plain store (NT A/B)
    }
}

// pre_softmax per (bn, j): A=Q (rows=qi), B=W=k2*k1row (cols=k); DMA'd images, W in regs
__device__ __forceinline__ void do_score(int sub, const float* __restrict__ k1,
                                         const short* __restrict__ ws,
                                         float* __restrict__ out, char* smem) {
    const int bn  = sub >> 7;
    const int j   = sub & 127;
    const int tid = threadIdx.x;
    const int lane = tid & 63;
    const int w    = tid >> 6;
    const int lr   = lane & 15;
    const int lg   = lane >> 4;

    short* shQ  = (short*)smem;             // Q[q][h] bf16 swizzled, 16KB
    short* shK2 = (short*)smem + TT*DD;     // K2[k][h] bf16 swizzled, 16KB

    async_copy16k(ws + WS_Q  + (size_t)bn * 8192, shQ,  tid);
    async_copy16k(ws + WS_K2 + (size_t)bn * 8192, shK2, tid);

    // per-lane k1[j][h] values at fragment h-positions (L2-hot scalar loads)
    const float* k1r = k1 + (size_t)(bn*TT + j)*DD;
    float k1f[2][8];
#pragma unroll
    for (int ks = 0; ks < 2; ks++) {
        const f32x4 lo = *(const f32x4*)(k1r + ks * 32 + lg * 8);
        const f32x4 hi = *(const f32x4*)(k1r + ks * 32 + lg * 8 + 4);
        k1f[ks][0] = lo.x; k1f[ks][1] = lo.y; k1f[ks][2] = lo.z; k1f[ks][3] = lo.w;
        k1f[ks][4] = hi.x; k1f[ks][5] = hi.y; k1f[ks][6] = hi.z; k1f[ks][7] = hi.w;
    }
    __syncthreads();

    const int kbase = w * 32;
    short8b wf[2][2];                       // B-operand: W = bf16(k2bf * k1row)
#pragma unroll
    for (int nt = 0; nt < 2; nt++)
#pragma unroll
        for (int ks = 0; ks < 2; ks++) {
            const int k  = kbase + nt * 16 + lr;
            const int hh = ks * 32 + lg * 8;
            short8b k2f = *(const short8b*)&shK2[(k * DD + hh) ^ ((k & 7) << 3)];
            short8b f;
#pragma unroll
            for (int i = 0; i < 8; i++) f[i] = f2bf(bf2f(k2f[i]) * k1f[ks][i]);
            wf[nt][ks] = f;
        }
    f32x4 acc[2][8] = {};
#pragma unroll
    for (int qt8 = 0; qt8 < 8; qt8++) {
        const int qhi = qt8 * 16 + 15;
        if (qhi >= j && qhi >= kbase) {        // wave-uniform: some element may be live
            short8b qf[2];                      // A-operand: Q tile (qi = M dim)
#pragma unroll
            for (int ks = 0; ks < 2; ks++) {
                const int qi = qt8 * 16 + lr;
                const int hh = ks * 32 + lg * 8;
                qf[ks] = *(const short8b*)&shQ[(qi * DD + hh) ^ ((qi & 7) << 3)];
            }
#pragma unroll
            for (int nt = 0; nt < 2; nt++)
                if (qhi >= kbase + nt * 16)    // nt sub-tile not fully masked
#pragma unroll
                    for (int ks = 0; ks < 2; ks++)
                        acc[nt][qt8] = __builtin_amdgcn_mfma_f32_16x16x32_bf16(qf[ks], wf[nt][ks], acc[nt][qt8], 0, 0, 0);
        }
    }

    float* dst = out + OFF_PRE + (size_t)sub*TT*TT;   // [k][q], q innermost
#pragma unroll
    for (int nt = 0; nt < 2; nt++) {
        const int k = kbase + nt * 16 + lr;           // D col = k (per-lane row in memory)
#pragma unroll
        for (int qt8 = 0; qt8 < 8; qt8++) {
            const int q0 = qt8 * 16 + lg * 4;         // D rows = 4 consecutive qi
            f32x4 v;
#pragma unroll
            for (int r = 0; r < 4; r++) {
                const int qi = q0 + r;
                v[r] = ((j <= qi) && (k <= qi)) ? acc[nt][qt8][r] : NEGF;
            }
            *(f32x4*)(dst + (size_t)k * TT + q0) = v;   // plain store (NT A/B)
        }
    }
}

// z, M, L per (bn, q): balanced j-tiles across waves, all-DMA staging, wave-local softmax
__device__ __forceinline__ void do_z(int sub, const float* __restrict__ q,
                                     const short* __restrict__ ws,
                                     float* __restrict__ out, char* smem) {
    const int bn  = sub >> 7;
    const int qq  = sub & 127;
    const int tid = threadIdx.x;
    const int w    = tid >> 6;
    const int lane = tid & 63;
    const int lr   = lane & 15;
    const int lg   = lane >> 4;

    short* shK1  = (short*)smem;                    // 16KB K1[j][h]; phase2: P rows 0-63
    short* shK2  = (short*)(smem + 16384);          // 16KB K2[k][h]; phase2: P rows 64-127
    short* shG2T = (short*)(smem + 32768);          // 16KB G2T[h][k]
    float* zred  = (float*)(smem + 49152);          // 4*64 floats = 1KB
    float* scrMax = (float*)(smem + 50176);         // 4
    float* scrSum = (float*)(smem + 50192);         // 4
    short* shP = shK1;                              // P[128][128] bf16 swz (32KB union)

    const float* qrow = q  + (size_t)sub * DD;
    const short* wsG1 = ws + WS_G1 + (size_t)bn * 8192;

    const int T_j   = (qq >> 4) + 1;           // live 16-row j tiles
    const int kslim = (qq >> 5) + 1;           // live 32-wide k blocks (phase 2)
    const int ktlim = kslim << 1;              // live 16-wide k tiles (phase 1)

    // ---- stage: async DMAs of only the live rows ----
    async_copy_chunks(ws + WS_K1  + (size_t)bn * 8192, shK1, tid, T_j << 1);
    async_copy_chunks(ws + WS_K2  + (size_t)bn * 8192, shK2, tid, kslim << 2);
    async_copy16k(ws + WS_G2T + (size_t)bn * 8192, shG2T, tid);

    // per-lane q scalars at fragment h-positions (L2-hot)
    float qs[2][8];
#pragma unroll
    for (int ks = 0; ks < 2; ks++) {
        const f32x4 lo = *(const f32x4*)(qrow + ks * 32 + lg * 8);
        const f32x4 hi = *(const f32x4*)(qrow + ks * 32 + lg * 8 + 4);
        qs[ks][0] = lo.x; qs[ks][1] = lo.y; qs[ks][2] = lo.z; qs[ks][3] = lo.w;
        qs[ks][4] = hi.x; qs[ks][5] = hi.y; qs[ks][6] = hi.z; qs[ks][7] = hi.w;
    }
    __syncthreads();                                   // B0: DMAs landed

    // wave w owns j-tile slots {w, w+4} (16 rows each), balanced across waves
    const int  tjs[2]  = { w, w + 4 };
    const bool live[2] = { tjs[0] < T_j, tjs[1] < T_j };

    // ---- phase 1 (A-fragments formed in regs from K1 image * q) ----
    float m = -3.4e38f;
    f32x4 acc[2][8] = {};
    short8b af[2][2];
#pragma unroll
    for (int jt = 0; jt < 2; jt++)
        if (live[jt])
#pragma unroll
            for (int ks = 0; ks < 2; ks++) {
                const int j  = tjs[jt] * 16 + lr;
                const int hh = ks * 32 + lg * 8;
                short8b k1v = *(const short8b*)&shK1[(j * DD + hh) ^ ((j & 7) << 3)];
                short8b f;
#pragma unroll
                for (int i = 0; i < 8; i++) f[i] = f2bf(bf2f(k1v[i]) * qs[ks][i]);
                af[jt][ks] = f;
            }
#pragma unroll
    for (int kt = 0; kt < 8; kt++) {
        if (kt < ktlim && live[0]) {
            short8b bf[2];
#pragma unroll
            for (int ks = 0; ks < 2; ks++) {
                const int k  = kt * 16 + lr;
                const int hh = ks * 32 + lg * 8;
                bf[ks] = *(const short8b*)&shK2[(k * DD + hh) ^ ((k & 7) << 3)];
            }
#pragma unroll
            for (int ks = 0; ks < 2; ks++)
                acc[0][kt] = __builtin_amdgcn_mfma_f32_16x16x32_bf16(af[0][ks], bf[ks], acc[0][kt], 0, 0, 0);
            if (live[1])
#pragma unroll
                for (int ks = 0; ks < 2; ks++)
                    acc[1][kt] = __builtin_amdgcn_mfma_f32_16x16x32_bf16(af[1][ks], bf[ks], acc[1][kt], 0, 0, 0);
        }
    }
    // mask + scale + wave-local max
#pragma unroll
    for (int jt = 0; jt < 2; jt++)
        if (live[jt])
#pragma unroll
            for (int kt = 0; kt < 8; kt++)
                if (kt < ktlim)
#pragma unroll
                    for (int r = 0; r < 4; r++) {
                        const int j = tjs[jt] * 16 + lg * 4 + r;
                        const int k = kt * 16 + lr;
                        float sv = ((j <= qq) && (k <= qq)) ? acc[jt][kt][r] * SCALE : (NEGF * SCALE);
                        acc[jt][kt][r] = sv;
                        m = fmaxf(m, sv);
                    }
#pragma unroll
    for (int off = 32; off >= 1; off >>= 1) m = fmaxf(m, __shfl_xor(m, off));
    // exp with WAVE-LOCAL max (pre-barrier; global rescale folded into epilogue)
    float ssum = 0.f;
#pragma unroll
    for (int jt = 0; jt < 2; jt++)
        if (live[jt])
#pragma unroll
            for (int kt = 0; kt < 8; kt++)
                if (kt < ktlim)
#pragma unroll
                    for (int r = 0; r < 4; r++) {
                        float p = __expf(acc[jt][kt][r] - m);   // masked -> exactly 0
                        acc[jt][kt][r] = p;
                        ssum += p;
                    }
#pragma unroll
    for (int off = 32; off >= 1; off >>= 1) ssum += __shfl_xor(ssum, off);
    if (lane == 0) { scrMax[w] = m; scrSum[w] = ssum; }
    __syncthreads();                                   // B1: K1/K2 reads done; scr ready

    const float M = fmaxf(fmaxf(scrMax[0], scrMax[1]), fmaxf(scrMax[2], scrMax[3]));
    float S = 0.f;
#pragma unroll
    for (int w4 = 0; w4 < 4; w4++) S += scrSum[w4] * __expf(scrMax[w4] - M);
    const float cw = __expf(m - M);                    // wave's rescale factor

    // ---- P write (own rows only) + phase 2 (reads own P rows + G2T) ----
    float zp[4] = {0.f, 0.f, 0.f, 0.f};
#pragma unroll
    for (int jt = 0; jt < 2; jt++)
        if (live[jt])
#pragma unroll
            for (int kt = 0; kt < 8; kt++)
                if (kt < ktlim)
#pragma unroll
                    for (int r = 0; r < 4; r++) {
                        const int j = tjs[jt] * 16 + lg * 4 + r;
                        const int k = kt * 16 + lr;
                        shP[(j * TT + k) ^ ((j & 7) << 3)] = f2bf(acc[jt][kt][r]);
                    }
    short8b pa[2][4];
#pragma unroll
    for (int jt = 0; jt < 2; jt++)
        if (live[jt])
#pragma unroll
            for (int ks = 0; ks < 4; ks++)
                if (ks < kslim) {
                    const int j  = tjs[jt] * 16 + lr;
                    const int kk = ks * 32 + lg * 8;
                    pa[jt][ks] = *(const short8b*)&shP[(j * TT + kk) ^ ((j & 7) << 3)];
                }
    f32x4 racc[2][4] = {};
#pragma unroll
    for (int ht = 0; ht < 4; ht++)
#pragma unroll
        for (int ks = 0; ks < 4; ks++)
            if (ks < kslim && live[0]) {
                const int h  = ht * 16 + lr;
                const int kk = ks * 32 + lg * 8;
                short8b gb = *(const short8b*)&shG2T[(h * TT + kk) ^ ((h & 7) << 3)];
                racc[0][ht] = __builtin_amdgcn_mfma_f32_16x16x32_bf16(pa[0][ks], gb, racc[0][ht], 0, 0, 0);
                if (live[1])
                    racc[1][ht] = __builtin_amdgcn_mfma_f32_16x16x32_bf16(pa[1][ks], gb, racc[1][ht], 0, 0, 0);
            }
#pragma unroll
    for (int jt = 0; jt < 2; jt++)
        if (live[jt])
#pragma unroll
            for (int ht = 0; ht < 4; ht++)
#pragma unroll
                for (int r = 0; r < 4; r++) {
                    const int j = tjs[jt] * 16 + lg * 4 + r;
                    const int h = ht * 16 + lr;
                    zp[ht] += bf2f(wsG1[j * DD + h]) * racc[jt][ht][r];
                }
#pragma unroll
    for (int ht = 0; ht < 4; ht++) {
        zp[ht] *= cw;                                  // fold exp(m_w - M) here
        zp[ht] += __shfl_xor(zp[ht], 16);
        zp[ht] += __shfl_xor(zp[ht], 32);
    }
    if (lg == 0) {
#pragma unroll
        for (int ht = 0; ht < 4; ht++) zred[w * DD + ht * 16 + lr] = zp[ht];
    }
    __syncthreads();                                   // B2
    if (tid < DD) {
        const float zs = zred[0*DD + tid] + zred[1*DD + tid] + zred[2*DD + tid] + zred[3*DD + tid];
        out[OFF_Z + (size_t)sub * DD + tid] = zs / S;
    }
    if (tid == 0) {
        out[OFF_M + (size_t)sub] = M;
        out[OFF_L + (size_t)sub] = S + 0.01f;
    }
}

__global__ __launch_bounds__(256) void k_fused(const float* __restrict__ q,
                                               const float* __restrict__ k1,
                                               const float* __restrict__ v1,
                                               const float* __restrict__ v2,
                                               const short* __restrict__ ws,
                                               float* __restrict__ out) {
    __shared__ __align__(16) char smem[50240];
    const int bid  = blockIdx.x;
    const int role = bid % 3;           // 3 coprime with 8 XCDs -> uniform role spread
    const int sub  = bid / 3;           // 0..4095
    if (role == 0)      do_z(sub, q, ws, out, smem);
    else if (role == 1) do_score(sub, k1, ws, out, smem);
    else                do_vg(sub, v1, v2, out, smem);
}

extern "C" void kernel_launch(void* const* d_in, const int* in_sizes, int n_in,
                              void* d_out, int out_size, void* d_ws, size_t ws_size,
                              hipStream_t stream) {
    (void)in_sizes; (void)n_in; (void)ws_size; (void)out_size;
    const float* q  = (const float*)d_in[0];
    const float* k1 = (const float*)d_in[1];
    const float* k2 = (const float*)d_in[2];
    const float* v1 = (const float*)d_in[3];
    const float* v2 = (const float*)d_in[4];
    float* out = (float*)d_out;
    short* ws = (short*)d_ws;

    k_prep<<<dim3(256), dim3(256), 0, stream>>>(q, k1, k2, v1, v2, ws);
    k_fused<<<dim3(3 * BHN * TT), dim3(256), 0, stream>>>(q, k1, v1, v2, ws, out);
}

// Round 17
// 88.939 us; speedup vs baseline: 1.2468x; 1.2468x over previous
//
#include <hip/hip_runtime.h>
#include <hip/hip_bf16.h>

#define TT 128
#define DD 64
#define BHN 32
#define SCALE 0.125f
#define NEGF -1000000.0f

// float-element offsets into d_out (concatenated return order: z, pre, vg, M, L)
#define OFF_Z   ((size_t)0)
#define OFF_PRE ((size_t)(BHN*TT*DD))                       // 262144
#define OFF_VG  (OFF_PRE + (size_t)BHN*TT*TT*TT)            // 67371008
#define OFF_M   (OFF_VG + (size_t)BHN*TT*TT*DD)             // 100925440
#define OFF_L   (OFF_M + (size_t)(BHN*TT))                  // 100929536

// workspace layout (short elements): pre-swizzled bf16 images, 2.5 MB total
#define WS_K2   ((size_t)0)           // [bn][8192] K2[k][h] bf16, XOR-swizzled
#define WS_G2T  ((size_t)262144)      // [bn][8192] G2T[h][k] bf16, XOR-swizzled
#define WS_Q    ((size_t)524288)      // [bn][8192] Q[q][h]  bf16, XOR-swizzled
#define WS_G1   ((size_t)786432)      // [bn][8192] silu(v1)[j][h] bf16, plain
#define WS_K1   ((size_t)1048576)     // [bn][8192] K1[j][h] bf16, XOR-swizzled

typedef __attribute__((ext_vector_type(8))) short short8b;   // 8 bf16 (4 VGPRs)
typedef __attribute__((ext_vector_type(4))) short short4b;
typedef __attribute__((ext_vector_type(4))) float f32x4;

__device__ __forceinline__ short f2bf(float f) {
    __hip_bfloat16 h = __float2bfloat16(f);
    return *reinterpret_cast<short*>(&h);
}
__device__ __forceinline__ float bf2f(short s) {
    union { unsigned u; float f; } v; v.u = ((unsigned)(unsigned short)s) << 16;
    return v.f;
}

// async copy of the first nchunks KB of a 16KB linear image -> LDS (linear).
// chunk c handled by wave c%4; lane l moves 16B.
__device__ __forceinline__ void async_copy_chunks(const short* __restrict__ src, short* dst,
                                                  int tid, int nchunks) {
    const int w    = tid >> 6;
    const int lane = tid & 63;
    const char* s = (const char*)src + lane * 16;
    char* d = (char*)dst;
#pragma unroll
    for (int i = 0; i < 4; i++) {
        const int c = (i << 2) + w;
        if (c < nchunks)
            __builtin_amdgcn_global_load_lds(
                (const __attribute__((address_space(1))) void*)(s + c * 1024),
                (__attribute__((address_space(3))) void*)(d + c * 1024), 16, 0, 0);
    }
}
__device__ __forceinline__ void async_copy16k(const short* __restrict__ src, short* dst, int tid) {
    async_copy_chunks(src, dst, tid, 16);
}

// ---------------- prep: once-per-(b,n) conversions into d_ws ----------------
__global__ __launch_bounds__(256) void k_prep(const float* __restrict__ q,
                                              const float* __restrict__ k1,
                                              const float* __restrict__ k2,
                                              const float* __restrict__ v1,
                                              const float* __restrict__ v2,
                                              short* __restrict__ ws) {
    const int bid   = blockIdx.x;     // 256 = 32 bn x 8 slices
    const int bn    = bid >> 3;
    const int slice = bid & 7;
    const int tid   = threadIdx.x;
    const int e4 = slice * 256 + tid; // 0..2047
    const int e  = e4 * 4;
    const int r  = e >> 6;
    const int h  = e & 63;
    const size_t g = (size_t)bn * TT * DD + e;

    short* wsK2  = ws + WS_K2  + (size_t)bn * 8192;
    short* wsG2T = ws + WS_G2T + (size_t)bn * 8192;
    short* wsQ   = ws + WS_Q   + (size_t)bn * 8192;
    short* wsG1  = ws + WS_G1  + (size_t)bn * 8192;
    short* wsK1  = ws + WS_K1  + (size_t)bn * 8192;

    const f32x4 k2v = *(const f32x4*)(k2 + g);
    const f32x4 k1v = *(const f32x4*)(k1 + g);
    const f32x4 qv  = *(const f32x4*)(q  + g);
    const f32x4 v2v = *(const f32x4*)(v2 + g);
    const f32x4 v1v = *(const f32x4*)(v1 + g);

    short4b kb, ab, qb, gb;
    kb[0] = f2bf(k2v.x); kb[1] = f2bf(k2v.y); kb[2] = f2bf(k2v.z); kb[3] = f2bf(k2v.w);
    ab[0] = f2bf(k1v.x); ab[1] = f2bf(k1v.y); ab[2] = f2bf(k1v.z); ab[3] = f2bf(k1v.w);
    qb[0] = f2bf(qv.x);  qb[1] = f2bf(qv.y);  qb[2] = f2bf(qv.z);  qb[3] = f2bf(qv.w);
#pragma unroll
    for (int i = 0; i < 4; i++) {
        float x = v1v[i];
        gb[i] = f2bf(x / (1.f + __expf(-x)));
    }
    const int idx = e ^ ((r & 7) << 3);
    *(short4b*)&wsK2[idx] = kb;
    *(short4b*)&wsK1[idx] = ab;
    *(short4b*)&wsQ[idx]  = qb;
    *(short4b*)&wsG1[e]   = gb;
    wsG2T[((h + 0) * TT + r) ^ (((h + 0) & 7) << 3)] = f2bf(v2v.x);
    wsG2T[((h + 1) * TT + r) ^ (((h + 1) & 7) << 3)] = f2bf(v2v.y);
    wsG2T[((h + 2) * TT + r) ^ (((h + 2) & 7) << 3)] = f2bf(v2v.z);
    wsG2T[((h + 3) * TT + r) ^ (((h + 3) & 7) << 3)] = f2bf(v2v.w);
}

// ---- role bodies (inlined into the fused kernel; smem is the 50KB union) ----

__device__ __forceinline__ void do_vg(int sub, const float* __restrict__ v1,
                                      const float* __restrict__ v2,
                                      float* __restrict__ out, char* smem) {
    const int bn  = sub >> 7;
    const int p   = sub & 127;
    const int tid = threadIdx.x;
    float* g1 = (float*)smem;              // [64]
    if (tid < DD) {
        float x = v1[(size_t)(bn*TT + p)*DD + tid];
        g1[tid] = x / (1.0f + __expf(-x));
    }
    __syncthreads();
    const f32x4* v2f = (const f32x4*)(v2 + (size_t)bn*TT*DD);
    float* dst = out + OFF_VG + (size_t)sub*TT*DD;
    const f32x4* g14 = (const f32x4*)g1;
    for (int i = tid; i < TT*DD/4; i += 256) {
        int h4 = i & 15;
        f32x4 v = v2f[i];
        f32x4 g = g14[h4];
        f32x4 r = v * g;
        __builtin_nontemporal_store(r, (f32x4*)(dst) + i);   // NT restored (R14: plain hurt)
    }
}

// pre_softmax per (bn, j): A=Q (rows=qi), B=W=k2*k1row (cols=k); DMA'd images, W in regs.
// Epilogue: LDS-staged, fully-coalesced NT stores (1KB/wave-instruction).
__device__ __forceinline__ void do_score(int sub, const float* __restrict__ k1,
                                         const short* __restrict__ ws,
                                         float* __restrict__ out, char* smem) {
    const int bn  = sub >> 7;
    const int j   = sub & 127;
    const int tid = threadIdx.x;
    const int lane = tid & 63;
    const int w    = tid >> 6;
    const int lr   = lane & 15;
    const int lg   = lane >> 4;

    short* shQ  = (short*)smem;             // Q[q][h] bf16 swizzled, 16KB
    short* shK2 = (short*)smem + TT*DD;     // K2[k][h] bf16 swizzled, 16KB

    async_copy16k(ws + WS_Q  + (size_t)bn * 8192, shQ,  tid);
    async_copy16k(ws + WS_K2 + (size_t)bn * 8192, shK2, tid);

    // per-lane k1[j][h] values at fragment h-positions (L2-hot scalar loads)
    const float* k1r = k1 + (size_t)(bn*TT + j)*DD;
    float k1f[2][8];
#pragma unroll
    for (int ks = 0; ks < 2; ks++) {
        const f32x4 lo = *(const f32x4*)(k1r + ks * 32 + lg * 8);
        const f32x4 hi = *(const f32x4*)(k1r + ks * 32 + lg * 8 + 4);
        k1f[ks][0] = lo.x; k1f[ks][1] = lo.y; k1f[ks][2] = lo.z; k1f[ks][3] = lo.w;
        k1f[ks][4] = hi.x; k1f[ks][5] = hi.y; k1f[ks][6] = hi.z; k1f[ks][7] = hi.w;
    }
    __syncthreads();

    const int kbase = w * 32;
    short8b wf[2][2];                       // B-operand: W = bf16(k2bf * k1row)
#pragma unroll
    for (int nt = 0; nt < 2; nt++)
#pragma unroll
        for (int ks = 0; ks < 2; ks++) {
            const int k  = kbase + nt * 16 + lr;
            const int hh = ks * 32 + lg * 8;
            short8b k2f = *(const short8b*)&shK2[(k * DD + hh) ^ ((k & 7) << 3)];
            short8b f;
#pragma unroll
            for (int i = 0; i < 8; i++) f[i] = f2bf(bf2f(k2f[i]) * k1f[ks][i]);
            wf[nt][ks] = f;
        }
    f32x4 acc[2][8] = {};
#pragma unroll
    for (int qt8 = 0; qt8 < 8; qt8++) {
        const int qhi = qt8 * 16 + 15;
        if (qhi >= j && qhi >= kbase) {        // wave-uniform: some element may be live
            short8b qf[2];                      // A-operand: Q tile (qi = M dim)
#pragma unroll
            for (int ks = 0; ks < 2; ks++) {
                const int qi = qt8 * 16 + lr;
                const int hh = ks * 32 + lg * 8;
                qf[ks] = *(const short8b*)&shQ[(qi * DD + hh) ^ ((qi & 7) << 3)];
            }
#pragma unroll
            for (int nt = 0; nt < 2; nt++)
                if (qhi >= kbase + nt * 16)    // nt sub-tile not fully masked
#pragma unroll
                    for (int ks = 0; ks < 2; ks++)
                        acc[nt][qt8] = __builtin_amdgcn_mfma_f32_16x16x32_bf16(qf[ks], wf[nt][ks], acc[nt][qt8], 0, 0, 0);
        }
    }

    // ---- epilogue: stage masked tile to LDS, then fully-coalesced NT stores ----
    __syncthreads();                        // all waves done reading shQ/shK2
    float* stg = (float*)smem + w * (16 * 132);   // wave-private [16][132] f32 (8448B)
    float* dst = out + OFF_PRE + (size_t)sub*TT*TT;   // [k][q], q innermost
#pragma unroll
    for (int nt = 0; nt < 2; nt++) {
        const int k = kbase + nt * 16 + lr;
#pragma unroll
        for (int qt8 = 0; qt8 < 8; qt8++) {
            const int q0 = qt8 * 16 + lg * 4;
            f32x4 v;
#pragma unroll
            for (int r = 0; r < 4; r++) {
                const int qi = q0 + r;
                v[r] = ((j <= qi) && (k <= qi)) ? acc[nt][qt8][r] : NEGF;
            }
            *(f32x4*)&stg[lr * 132 + q0] = v;
        }
        // wave region = 16 contiguous k-rows = 8KB contiguous in global
        float* gbase = dst + (size_t)(kbase + nt * 16) * TT;
#pragma unroll
        for (int i = 0; i < 8; i++) {
            const int row  = i * 2 + (lane >> 5);
            const int colf = (lane & 31) * 4;
            f32x4 v = *(const f32x4*)&stg[row * 132 + colf];
            __builtin_nontemporal_store(v, (f32x4*)(gbase + i * 256 + lane * 4));
        }
    }
}

// z, M, L per (bn, q): balanced j-tiles across waves, all-DMA staging, wave-local softmax
__device__ __forceinline__ void do_z(int sub, const float* __restrict__ q,
                                     const short* __restrict__ ws,
                                     float* __restrict__ out, char* smem) {
    const int bn  = sub >> 7;
    const int qq  = sub & 127;
    const int tid = threadIdx.x;
    const int w    = tid >> 6;
    const int lane = tid & 63;
    const int lr   = lane & 15;
    const int lg   = lane >> 4;

    short* shK1  = (short*)smem;                    // 16KB K1[j][h]; phase2: P rows 0-63
    short* shK2  = (short*)(smem + 16384);          // 16KB K2[k][h]; phase2: P rows 64-127
    short* shG2T = (short*)(smem + 32768);          // 16KB G2T[h][k]
    float* zred  = (float*)(smem + 49152);          // 4*64 floats = 1KB
    float* scrMax = (float*)(smem + 50176);         // 4
    float* scrSum = (float*)(smem + 50192);         // 4
    short* shP = shK1;                              // P[128][128] bf16 swz (32KB union)

    const float* qrow = q  + (size_t)sub * DD;
    const short* wsG1 = ws + WS_G1 + (size_t)bn * 8192;

    const int T_j   = (qq >> 4) + 1;           // live 16-row j tiles
    const int kslim = (qq >> 5) + 1;           // live 32-wide k blocks (phase 2)
    const int ktlim = kslim << 1;              // live 16-wide k tiles (phase 1)

    // ---- stage: async DMAs of only the live rows ----
    async_copy_chunks(ws + WS_K1  + (size_t)bn * 8192, shK1, tid, T_j << 1);
    async_copy_chunks(ws + WS_K2  + (size_t)bn * 8192, shK2, tid, kslim << 2);
    async_copy16k(ws + WS_G2T + (size_t)bn * 8192, shG2T, tid);

    // per-lane q scalars at fragment h-positions (L2-hot)
    float qs[2][8];
#pragma unroll
    for (int ks = 0; ks < 2; ks++) {
        const f32x4 lo = *(const f32x4*)(qrow + ks * 32 + lg * 8);
        const f32x4 hi = *(const f32x4*)(qrow + ks * 32 + lg * 8 + 4);
        qs[ks][0] = lo.x; qs[ks][1] = lo.y; qs[ks][2] = lo.z; qs[ks][3] = lo.w;
        qs[ks][4] = hi.x; qs[ks][5] = hi.y; qs[ks][6] = hi.z; qs[ks][7] = hi.w;
    }
    __syncthreads();                                   // B0: DMAs landed

    // wave w owns j-tile slots {w, w+4} (16 rows each), balanced across waves
    const int  tjs[2]  = { w, w + 4 };
    const bool live[2] = { tjs[0] < T_j, tjs[1] < T_j };

    // ---- phase 1 (A-fragments formed in regs from K1 image * q) ----
    float m = -3.4e38f;
    f32x4 acc[2][8] = {};
    short8b af[2][2];
#pragma unroll
    for (int jt = 0; jt < 2; jt++)
        if (live[jt])
#pragma unroll
            for (int ks = 0; ks < 2; ks++) {
                const int j  = tjs[jt] * 16 + lr;
                const int hh = ks * 32 + lg * 8;
                short8b k1v = *(const short8b*)&shK1[(j * DD + hh) ^ ((j & 7) << 3)];
                short8b f;
#pragma unroll
                for (int i = 0; i < 8; i++) f[i] = f2bf(bf2f(k1v[i]) * qs[ks][i]);
                af[jt][ks] = f;
            }
#pragma unroll
    for (int kt = 0; kt < 8; kt++) {
        if (kt < ktlim && live[0]) {
            short8b bf[2];
#pragma unroll
            for (int ks = 0; ks < 2; ks++) {
                const int k  = kt * 16 + lr;
                const int hh = ks * 32 + lg * 8;
                bf[ks] = *(const short8b*)&shK2[(k * DD + hh) ^ ((k & 7) << 3)];
            }
#pragma unroll
            for (int ks = 0; ks < 2; ks++)
                acc[0][kt] = __builtin_amdgcn_mfma_f32_16x16x32_bf16(af[0][ks], bf[ks], acc[0][kt], 0, 0, 0);
            if (live[1])
#pragma unroll
                for (int ks = 0; ks < 2; ks++)
                    acc[1][kt] = __builtin_amdgcn_mfma_f32_16x16x32_bf16(af[1][ks], bf[ks], acc[1][kt], 0, 0, 0);
        }
    }
    // mask + scale + wave-local max
#pragma unroll
    for (int jt = 0; jt < 2; jt++)
        if (live[jt])
#pragma unroll
            for (int kt = 0; kt < 8; kt++)
                if (kt < ktlim)
#pragma unroll
                    for (int r = 0; r < 4; r++) {
                        const int j = tjs[jt] * 16 + lg * 4 + r;
                        const int k = kt * 16 + lr;
                        float sv = ((j <= qq) && (k <= qq)) ? acc[jt][kt][r] * SCALE : (NEGF * SCALE);
                        acc[jt][kt][r] = sv;
                        m = fmaxf(m, sv);
                    }
#pragma unroll
    for (int off = 32; off >= 1; off >>= 1) m = fmaxf(m, __shfl_xor(m, off));
    // exp with WAVE-LOCAL max (pre-barrier; global rescale folded into epilogue)
    float ssum = 0.f;
#pragma unroll
    for (int jt = 0; jt < 2; jt++)
        if (live[jt])
#pragma unroll
            for (int kt = 0; kt < 8; kt++)
                if (kt < ktlim)
#pragma unroll
                    for (int r = 0; r < 4; r++) {
                        float p = __expf(acc[jt][kt][r] - m);   // masked -> exactly 0
                        acc[jt][kt][r] = p;
                        ssum += p;
                    }
#pragma unroll
    for (int off = 32; off >= 1; off >>= 1) ssum += __shfl_xor(ssum, off);
    if (lane == 0) { scrMax[w] = m; scrSum[w] = ssum; }
    __syncthreads();                                   // B1: K1/K2 reads done; scr ready

    const float M = fmaxf(fmaxf(scrMax[0], scrMax[1]), fmaxf(scrMax[2], scrMax[3]));
    float S = 0.f;
#pragma unroll
    for (int w4 = 0; w4 < 4; w4++) S += scrSum[w4] * __expf(scrMax[w4] - M);
    const float cw = __expf(m - M);                    // wave's rescale factor

    // ---- P write (own rows only) + phase 2 (reads own P rows + G2T) ----
    float zp[4] = {0.f, 0.f, 0.f, 0.f};
#pragma unroll
    for (int jt = 0; jt < 2; jt++)
        if (live[jt])
#pragma unroll
            for (int kt = 0; kt < 8; kt++)
                if (kt < ktlim)
#pragma unroll
                    for (int r = 0; r < 4; r++) {
                        const int j = tjs[jt] * 16 + lg * 4 + r;
                        const int k = kt * 16 + lr;
                        shP[(j * TT + k) ^ ((j & 7) << 3)] = f2bf(acc[jt][kt][r]);
                    }
    short8b pa[2][4];
#pragma unroll
    for (int jt = 0; jt < 2; jt++)
        if (live[jt])
#pragma unroll
            for (int ks = 0; ks < 4; ks++)
                if (ks < kslim) {
                    const int j  = tjs[jt] * 16 + lr;
                    const int kk = ks * 32 + lg * 8;
                    pa[jt][ks] = *(const short8b*)&shP[(j * TT + kk) ^ ((j & 7) << 3)];
                }
    f32x4 racc[2][4] = {};
#pragma unroll
    for (int ht = 0; ht < 4; ht++)
#pragma unroll
        for (int ks = 0; ks < 4; ks++)
            if (ks < kslim && live[0]) {
                const int h  = ht * 16 + lr;
                const int kk = ks * 32 + lg * 8;
                short8b gb = *(const short8b*)&shG2T[(h * TT + kk) ^ ((h & 7) << 3)];
                racc[0][ht] = __builtin_amdgcn_mfma_f32_16x16x32_bf16(pa[0][ks], gb, racc[0][ht], 0, 0, 0);
                if (live[1])
                    racc[1][ht] = __builtin_amdgcn_mfma_f32_16x16x32_bf16(pa[1][ks], gb, racc[1][ht], 0, 0, 0);
            }
#pragma unroll
    for (int jt = 0; jt < 2; jt++)
        if (live[jt])
#pragma unroll
            for (int ht = 0; ht < 4; ht++)
#pragma unroll
                for (int r = 0; r < 4; r++) {
                    const int j = tjs[jt] * 16 + lg * 4 + r;
                    const int h = ht * 16 + lr;
                    zp[ht] += bf2f(wsG1[j * DD + h]) * racc[jt][ht][r];
                }
#pragma unroll
    for (int ht = 0; ht < 4; ht++) {
        zp[ht] *= cw;                                  // fold exp(m_w - M) here
        zp[ht] += __shfl_xor(zp[ht], 16);
        zp[ht] += __shfl_xor(zp[ht], 32);
    }
    if (lg == 0) {
#pragma unroll
        for (int ht = 0; ht < 4; ht++) zred[w * DD + ht * 16 + lr] = zp[ht];
    }
    __syncthreads();                                   // B2
    if (tid < DD) {
        const float zs = zred[0*DD + tid] + zred[1*DD + tid] + zred[2*DD + tid] + zred[3*DD + tid];
        out[OFF_Z + (size_t)sub * DD + tid] = zs / S;
    }
    if (tid == 0) {
        out[OFF_M + (size_t)sub] = M;
        out[OFF_L + (size_t)sub] = S + 0.01f;
    }
}

__global__ __launch_bounds__(256) void k_fused(const float* __restrict__ q,
                                               const float* __restrict__ k1,
                                               const float* __restrict__ v1,
                                               const float* __restrict__ v2,
                                               const short* __restrict__ ws,
                                               float* __restrict__ out) {
    __shared__ __align__(16) char smem[50240];
    const int bid  = blockIdx.x;
    const int role = bid % 3;           // 3 coprime with 8 XCDs -> uniform role spread
    const int sub  = bid / 3;           // 0..4095
    if (role == 0)      do_z(sub, q, ws, out, smem);
    else if (role == 1) do_score(sub, k1, ws, out, smem);
    else                do_vg(sub, v1, v2, out, smem);
}

extern "C" void kernel_launch(void* const* d_in, const int* in_sizes, int n_in,
                              void* d_out, int out_size, void* d_ws, size_t ws_size,
                              hipStream_t stream) {
    (void)in_sizes; (void)n_in; (void)ws_size; (void)out_size;
    const float* q  = (const float*)d_in[0];
    const float* k1 = (const float*)d_in[1];
    const float* k2 = (const float*)d_in[2];
    const float* v1 = (const float*)d_in[3];
    const float* v2 = (const float*)d_in[4];
    float* out = (float*)d_out;
    short* ws = (short*)d_ws;

    k_prep<<<dim3(256), dim3(256), 0, stream>>>(q, k1, k2, v1, v2, ws);
    k_fused<<<dim3(3 * BHN * TT), dim3(256), 0, stream>>>(q, k1, v1, v2, ws, out);
}

// Round 18
// 80.332 us; speedup vs baseline: 1.3804x; 1.1071x over previous
//
#include <hip/hip_runtime.h>
#include <hip/hip_bf16.h>

#define TT 128
#define DD 64
#define BHN 32
#define SCALE 0.125f
#define NEGF -1000000.0f

// float-element offsets into d_out (concatenated return order: z, pre, vg, M, L)
#define OFF_Z   ((size_t)0)
#define OFF_PRE ((size_t)(BHN*TT*DD))                       // 262144
#define OFF_VG  (OFF_PRE + (size_t)BHN*TT*TT*TT)            // 67371008
#define OFF_M   (OFF_VG + (size_t)BHN*TT*TT*DD)             // 100925440
#define OFF_L   (OFF_M + (size_t)(BHN*TT))                  // 100929536

// workspace layout (short elements): pre-swizzled bf16 images, 2.5 MB total
#define WS_K2   ((size_t)0)           // [bn][8192] K2[k][h] bf16, XOR-swizzled
#define WS_G2T  ((size_t)262144)      // [bn][8192] G2T[h][k] bf16, XOR-swizzled
#define WS_Q    ((size_t)524288)      // [bn][8192] Q[q][h]  bf16, XOR-swizzled
#define WS_G1   ((size_t)786432)      // [bn][8192] silu(v1)[j][h] bf16, plain
#define WS_K1   ((size_t)1048576)     // [bn][8192] K1[j][h] bf16, XOR-swizzled

typedef __attribute__((ext_vector_type(8))) short short8b;   // 8 bf16 (4 VGPRs)
typedef __attribute__((ext_vector_type(4))) short short4b;
typedef __attribute__((ext_vector_type(4))) float f32x4;

__device__ __forceinline__ short f2bf(float f) {
    __hip_bfloat16 h = __float2bfloat16(f);
    return *reinterpret_cast<short*>(&h);
}
__device__ __forceinline__ float bf2f(short s) {
    union { unsigned u; float f; } v; v.u = ((unsigned)(unsigned short)s) << 16;
    return v.f;
}

// async copy of the first nchunks KB of a 16KB linear image -> LDS (linear).
// chunk c handled by wave c%4; lane l moves 16B.
__device__ __forceinline__ void async_copy_chunks(const short* __restrict__ src, short* dst,
                                                  int tid, int nchunks) {
    const int w    = tid >> 6;
    const int lane = tid & 63;
    const char* s = (const char*)src + lane * 16;
    char* d = (char*)dst;
#pragma unroll
    for (int i = 0; i < 4; i++) {
        const int c = (i << 2) + w;
        if (c < nchunks)
            __builtin_amdgcn_global_load_lds(
                (const __attribute__((address_space(1))) void*)(s + c * 1024),
                (__attribute__((address_space(3))) void*)(d + c * 1024), 16, 0, 0);
    }
}
__device__ __forceinline__ void async_copy16k(const short* __restrict__ src, short* dst, int tid) {
    async_copy_chunks(src, dst, tid, 16);
}

// ---------------- prep: once-per-(b,n) conversions into d_ws ----------------
__global__ __launch_bounds__(256) void k_prep(const float* __restrict__ q,
                                              const float* __restrict__ k1,
                                              const float* __restrict__ k2,
                                              const float* __restrict__ v1,
                                              const float* __restrict__ v2,
                                              short* __restrict__ ws) {
    const int bid   = blockIdx.x;     // 256 = 32 bn x 8 slices
    const int bn    = bid >> 3;
    const int slice = bid & 7;
    const int tid   = threadIdx.x;
    const int e4 = slice * 256 + tid; // 0..2047
    const int e  = e4 * 4;
    const int r  = e >> 6;
    const int h  = e & 63;
    const size_t g = (size_t)bn * TT * DD + e;

    short* wsK2  = ws + WS_K2  + (size_t)bn * 8192;
    short* wsG2T = ws + WS_G2T + (size_t)bn * 8192;
    short* wsQ   = ws + WS_Q   + (size_t)bn * 8192;
    short* wsG1  = ws + WS_G1  + (size_t)bn * 8192;
    short* wsK1  = ws + WS_K1  + (size_t)bn * 8192;

    const f32x4 k2v = *(const f32x4*)(k2 + g);
    const f32x4 k1v = *(const f32x4*)(k1 + g);
    const f32x4 qv  = *(const f32x4*)(q  + g);
    const f32x4 v2v = *(const f32x4*)(v2 + g);
    const f32x4 v1v = *(const f32x4*)(v1 + g);

    short4b kb, ab, qb, gb;
    kb[0] = f2bf(k2v.x); kb[1] = f2bf(k2v.y); kb[2] = f2bf(k2v.z); kb[3] = f2bf(k2v.w);
    ab[0] = f2bf(k1v.x); ab[1] = f2bf(k1v.y); ab[2] = f2bf(k1v.z); ab[3] = f2bf(k1v.w);
    qb[0] = f2bf(qv.x);  qb[1] = f2bf(qv.y);  qb[2] = f2bf(qv.z);  qb[3] = f2bf(qv.w);
#pragma unroll
    for (int i = 0; i < 4; i++) {
        float x = v1v[i];
        gb[i] = f2bf(x / (1.f + __expf(-x)));
    }
    const int idx = e ^ ((r & 7) << 3);
    *(short4b*)&wsK2[idx] = kb;
    *(short4b*)&wsK1[idx] = ab;
    *(short4b*)&wsQ[idx]  = qb;
    *(short4b*)&wsG1[e]   = gb;
    wsG2T[((h + 0) * TT + r) ^ (((h + 0) & 7) << 3)] = f2bf(v2v.x);
    wsG2T[((h + 1) * TT + r) ^ (((h + 1) & 7) << 3)] = f2bf(v2v.y);
    wsG2T[((h + 2) * TT + r) ^ (((h + 2) & 7) << 3)] = f2bf(v2v.z);
    wsG2T[((h + 3) * TT + r) ^ (((h + 3) & 7) << 3)] = f2bf(v2v.w);
}

// ---- role bodies (inlined into the fused kernel; smem is the 33.9KB union) ----

__device__ __forceinline__ void do_vg(int sub, const float* __restrict__ v1,
                                      const float* __restrict__ v2,
                                      float* __restrict__ out, char* smem) {
    const int bn  = sub >> 7;
    const int p   = sub & 127;
    const int tid = threadIdx.x;
    float* g1 = (float*)smem;              // [64]
    if (tid < DD) {
        float x = v1[(size_t)(bn*TT + p)*DD + tid];
        g1[tid] = x / (1.0f + __expf(-x));
    }
    __syncthreads();
    const f32x4* v2f = (const f32x4*)(v2 + (size_t)bn*TT*DD);
    float* dst = out + OFF_VG + (size_t)sub*TT*DD;
    const f32x4* g14 = (const f32x4*)g1;
    for (int i = tid; i < TT*DD/4; i += 256) {
        int h4 = i & 15;
        f32x4 v = v2f[i];
        f32x4 g = g14[h4];
        f32x4 r = v * g;
        __builtin_nontemporal_store(r, (f32x4*)(dst) + i);
    }
}

// pre_softmax per (bn, j): A=Q (rows=qi), B=W=k2*k1row (cols=k); DMA'd images, W in regs.
// Epilogue: LDS-staged, fully-coalesced NT stores (1KB/wave-instruction).
__device__ __forceinline__ void do_score(int sub, const float* __restrict__ k1,
                                         const short* __restrict__ ws,
                                         float* __restrict__ out, char* smem) {
    const int bn  = sub >> 7;
    const int j   = sub & 127;
    const int tid = threadIdx.x;
    const int lane = tid & 63;
    const int w    = tid >> 6;
    const int lr   = lane & 15;
    const int lg   = lane >> 4;

    short* shQ  = (short*)smem;             // Q[q][h] bf16 swizzled, 16KB
    short* shK2 = (short*)smem + TT*DD;     // K2[k][h] bf16 swizzled, 16KB

    async_copy16k(ws + WS_Q  + (size_t)bn * 8192, shQ,  tid);
    async_copy16k(ws + WS_K2 + (size_t)bn * 8192, shK2, tid);

    // per-lane k1[j][h] values at fragment h-positions (L2-hot scalar loads)
    const float* k1r = k1 + (size_t)(bn*TT + j)*DD;
    float k1f[2][8];
#pragma unroll
    for (int ks = 0; ks < 2; ks++) {
        const f32x4 lo = *(const f32x4*)(k1r + ks * 32 + lg * 8);
        const f32x4 hi = *(const f32x4*)(k1r + ks * 32 + lg * 8 + 4);
        k1f[ks][0] = lo.x; k1f[ks][1] = lo.y; k1f[ks][2] = lo.z; k1f[ks][3] = lo.w;
        k1f[ks][4] = hi.x; k1f[ks][5] = hi.y; k1f[ks][6] = hi.z; k1f[ks][7] = hi.w;
    }
    __syncthreads();

    const int kbase = w * 32;
    short8b wf[2][2];                       // B-operand: W = bf16(k2bf * k1row)
#pragma unroll
    for (int nt = 0; nt < 2; nt++)
#pragma unroll
        for (int ks = 0; ks < 2; ks++) {
            const int k  = kbase + nt * 16 + lr;
            const int hh = ks * 32 + lg * 8;
            short8b k2f = *(const short8b*)&shK2[(k * DD + hh) ^ ((k & 7) << 3)];
            short8b f;
#pragma unroll
            for (int i = 0; i < 8; i++) f[i] = f2bf(bf2f(k2f[i]) * k1f[ks][i]);
            wf[nt][ks] = f;
        }
    f32x4 acc[2][8] = {};
#pragma unroll
    for (int qt8 = 0; qt8 < 8; qt8++) {
        const int qhi = qt8 * 16 + 15;
        if (qhi >= j && qhi >= kbase) {        // wave-uniform: some element may be live
            short8b qf[2];                      // A-operand: Q tile (qi = M dim)
#pragma unroll
            for (int ks = 0; ks < 2; ks++) {
                const int qi = qt8 * 16 + lr;
                const int hh = ks * 32 + lg * 8;
                qf[ks] = *(const short8b*)&shQ[(qi * DD + hh) ^ ((qi & 7) << 3)];
            }
#pragma unroll
            for (int nt = 0; nt < 2; nt++)
                if (qhi >= kbase + nt * 16)    // nt sub-tile not fully masked
#pragma unroll
                    for (int ks = 0; ks < 2; ks++)
                        acc[nt][qt8] = __builtin_amdgcn_mfma_f32_16x16x32_bf16(qf[ks], wf[nt][ks], acc[nt][qt8], 0, 0, 0);
        }
    }

    // ---- epilogue: stage masked tile to LDS, then fully-coalesced NT stores ----
    __syncthreads();                        // all waves done reading shQ/shK2
    float* stg = (float*)smem + w * (16 * 132);   // wave-private [16][132] f32 (8448B)
    float* dst = out + OFF_PRE + (size_t)sub*TT*TT;   // [k][q], q innermost
#pragma unroll
    for (int nt = 0; nt < 2; nt++) {
        const int k = kbase + nt * 16 + lr;
#pragma unroll
        for (int qt8 = 0; qt8 < 8; qt8++) {
            const int q0 = qt8 * 16 + lg * 4;
            f32x4 v;
#pragma unroll
            for (int r = 0; r < 4; r++) {
                const int qi = q0 + r;
                v[r] = ((j <= qi) && (k <= qi)) ? acc[nt][qt8][r] : NEGF;
            }
            *(f32x4*)&stg[lr * 132 + q0] = v;
        }
        // wave region = 16 contiguous k-rows = 8KB contiguous in global
        float* gbase = dst + (size_t)(kbase + nt * 16) * TT;
#pragma unroll
        for (int i = 0; i < 8; i++) {
            const int row  = i * 2 + (lane >> 5);
            const int colf = (lane & 31) * 4;
            f32x4 v = *(const f32x4*)&stg[row * 132 + colf];
            __builtin_nontemporal_store(v, (f32x4*)(gbase + i * 256 + lane * 4));
        }
    }
}

// z, M, L per (bn, q): balanced j-tiles across waves; G2 fragments straight from L2-hot ws
__device__ __forceinline__ void do_z(int sub, const float* __restrict__ q,
                                     const short* __restrict__ ws,
                                     float* __restrict__ out, char* smem) {
    const int bn  = sub >> 7;
    const int qq  = sub & 127;
    const int tid = threadIdx.x;
    const int w    = tid >> 6;
    const int lane = tid & 63;
    const int lr   = lane & 15;
    const int lg   = lane >> 4;

    short* shK1  = (short*)smem;                    // 16KB K1[j][h]; phase2: P rows 0-63
    short* shK2  = (short*)(smem + 16384);          // 16KB K2[k][h]; phase2: P rows 64-127
    float* zred  = (float*)(smem + 32768);          // 4*64 floats = 1KB
    float* scrMax = (float*)(smem + 33792);         // 4
    float* scrSum = (float*)(smem + 33808);         // 4
    short* shP = shK1;                              // P[128][128] bf16 swz (32KB union)

    const float* qrow = q  + (size_t)sub * DD;
    const short* wsG1 = ws + WS_G1  + (size_t)bn * 8192;
    const short* wsG2 = ws + WS_G2T + (size_t)bn * 8192;   // read direct (L2-hot)

    const int T_j   = (qq >> 4) + 1;           // live 16-row j tiles
    const int kslim = (qq >> 5) + 1;           // live 32-wide k blocks (phase 2)
    const int ktlim = kslim << 1;              // live 16-wide k tiles (phase 1)

    // ---- stage: async DMAs of only the live rows (K1, K2 only; no G2T) ----
    async_copy_chunks(ws + WS_K1 + (size_t)bn * 8192, shK1, tid, T_j << 1);
    async_copy_chunks(ws + WS_K2 + (size_t)bn * 8192, shK2, tid, kslim << 2);

    // per-lane q scalars at fragment h-positions (L2-hot)
    float qs[2][8];
#pragma unroll
    for (int ks = 0; ks < 2; ks++) {
        const f32x4 lo = *(const f32x4*)(qrow + ks * 32 + lg * 8);
        const f32x4 hi = *(const f32x4*)(qrow + ks * 32 + lg * 8 + 4);
        qs[ks][0] = lo.x; qs[ks][1] = lo.y; qs[ks][2] = lo.z; qs[ks][3] = lo.w;
        qs[ks][4] = hi.x; qs[ks][5] = hi.y; qs[ks][6] = hi.z; qs[ks][7] = hi.w;
    }
    __syncthreads();                                   // B0: DMAs landed

    // wave w owns j-tile slots {w, w+4} (16 rows each), balanced across waves
    const int  tjs[2]  = { w, w + 4 };
    const bool live[2] = { tjs[0] < T_j, tjs[1] < T_j };

    // ---- phase 1 (A-fragments formed in regs from K1 image * q) ----
    float m = -3.4e38f;
    f32x4 acc[2][8] = {};
    short8b af[2][2];
#pragma unroll
    for (int jt = 0; jt < 2; jt++)
        if (live[jt])
#pragma unroll
            for (int ks = 0; ks < 2; ks++) {
                const int j  = tjs[jt] * 16 + lr;
                const int hh = ks * 32 + lg * 8;
                short8b k1v = *(const short8b*)&shK1[(j * DD + hh) ^ ((j & 7) << 3)];
                short8b f;
#pragma unroll
                for (int i = 0; i < 8; i++) f[i] = f2bf(bf2f(k1v[i]) * qs[ks][i]);
                af[jt][ks] = f;
            }
#pragma unroll
    for (int kt = 0; kt < 8; kt++) {
        if (kt < ktlim && live[0]) {
            short8b bf[2];
#pragma unroll
            for (int ks = 0; ks < 2; ks++) {
                const int k  = kt * 16 + lr;
                const int hh = ks * 32 + lg * 8;
                bf[ks] = *(const short8b*)&shK2[(k * DD + hh) ^ ((k & 7) << 3)];
            }
#pragma unroll
            for (int ks = 0; ks < 2; ks++)
                acc[0][kt] = __builtin_amdgcn_mfma_f32_16x16x32_bf16(af[0][ks], bf[ks], acc[0][kt], 0, 0, 0);
            if (live[1])
#pragma unroll
                for (int ks = 0; ks < 2; ks++)
                    acc[1][kt] = __builtin_amdgcn_mfma_f32_16x16x32_bf16(af[1][ks], bf[ks], acc[1][kt], 0, 0, 0);
        }
    }
    // mask + scale + wave-local max
#pragma unroll
    for (int jt = 0; jt < 2; jt++)
        if (live[jt])
#pragma unroll
            for (int kt = 0; kt < 8; kt++)
                if (kt < ktlim)
#pragma unroll
                    for (int r = 0; r < 4; r++) {
                        const int j = tjs[jt] * 16 + lg * 4 + r;
                        const int k = kt * 16 + lr;
                        float sv = ((j <= qq) && (k <= qq)) ? acc[jt][kt][r] * SCALE : (NEGF * SCALE);
                        acc[jt][kt][r] = sv;
                        m = fmaxf(m, sv);
                    }
#pragma unroll
    for (int off = 32; off >= 1; off >>= 1) m = fmaxf(m, __shfl_xor(m, off));
    // exp with WAVE-LOCAL max (pre-barrier; global rescale folded into epilogue)
    float ssum = 0.f;
#pragma unroll
    for (int jt = 0; jt < 2; jt++)
        if (live[jt])
#pragma unroll
            for (int kt = 0; kt < 8; kt++)
                if (kt < ktlim)
#pragma unroll
                    for (int r = 0; r < 4; r++) {
                        float p = __expf(acc[jt][kt][r] - m);   // masked -> exactly 0
                        acc[jt][kt][r] = p;
                        ssum += p;
                    }
#pragma unroll
    for (int off = 32; off >= 1; off >>= 1) ssum += __shfl_xor(ssum, off);
    if (lane == 0) { scrMax[w] = m; scrSum[w] = ssum; }
    __syncthreads();                                   // B1: K1/K2 reads done; scr ready

    const float M = fmaxf(fmaxf(scrMax[0], scrMax[1]), fmaxf(scrMax[2], scrMax[3]));
    float S = 0.f;
#pragma unroll
    for (int w4 = 0; w4 < 4; w4++) S += scrSum[w4] * __expf(scrMax[w4] - M);
    const float cw = __expf(m - M);                    // wave's rescale factor

    // ---- P write (own rows only) + phase 2 (own P rows; G2 fragments from ws/L2) ----
    float zp[4] = {0.f, 0.f, 0.f, 0.f};
#pragma unroll
    for (int jt = 0; jt < 2; jt++)
        if (live[jt])
#pragma unroll
            for (int kt = 0; kt < 8; kt++)
                if (kt < ktlim)
#pragma unroll
                    for (int r = 0; r < 4; r++) {
                        const int j = tjs[jt] * 16 + lg * 4 + r;
                        const int k = kt * 16 + lr;
                        shP[(j * TT + k) ^ ((j & 7) << 3)] = f2bf(acc[jt][kt][r]);
                    }
    short8b pa[2][4];
#pragma unroll
    for (int jt = 0; jt < 2; jt++)
        if (live[jt])
#pragma unroll
            for (int ks = 0; ks < 4; ks++)
                if (ks < kslim) {
                    const int j  = tjs[jt] * 16 + lr;
                    const int kk = ks * 32 + lg * 8;
                    pa[jt][ks] = *(const short8b*)&shP[(j * TT + kk) ^ ((j & 7) << 3)];
                }
    f32x4 racc[2][4] = {};
#pragma unroll
    for (int ht = 0; ht < 4; ht++)
#pragma unroll
        for (int ks = 0; ks < 4; ks++)
            if (ks < kslim && live[0]) {
                const int h  = ht * 16 + lr;
                const int kk = ks * 32 + lg * 8;
                short8b gb = *(const short8b*)&wsG2[(h * TT + kk) ^ ((h & 7) << 3)];
                racc[0][ht] = __builtin_amdgcn_mfma_f32_16x16x32_bf16(pa[0][ks], gb, racc[0][ht], 0, 0, 0);
                if (live[1])
                    racc[1][ht] = __builtin_amdgcn_mfma_f32_16x16x32_bf16(pa[1][ks], gb, racc[1][ht], 0, 0, 0);
            }
#pragma unroll
    for (int jt = 0; jt < 2; jt++)
        if (live[jt])
#pragma unroll
            for (int ht = 0; ht < 4; ht++)
#pragma unroll
                for (int r = 0; r < 4; r++) {
                    const int j = tjs[jt] * 16 + lg * 4 + r;
                    const int h = ht * 16 + lr;
                    zp[ht] += bf2f(wsG1[j * DD + h]) * racc[jt][ht][r];
                }
#pragma unroll
    for (int ht = 0; ht < 4; ht++) {
        zp[ht] *= cw;                                  // fold exp(m_w - M) here
        zp[ht] += __shfl_xor(zp[ht], 16);
        zp[ht] += __shfl_xor(zp[ht], 32);
    }
    if (lg == 0) {
#pragma unroll
        for (int ht = 0; ht < 4; ht++) zred[w * DD + ht * 16 + lr] = zp[ht];
    }
    __syncthreads();                                   // B2
    if (tid < DD) {
        const float zs = zred[0*DD + tid] + zred[1*DD + tid] + zred[2*DD + tid] + zred[3*DD + tid];
        out[OFF_Z + (size_t)sub * DD + tid] = zs / S;
    }
    if (tid == 0) {
        out[OFF_M + (size_t)sub] = M;
        out[OFF_L + (size_t)sub] = S + 0.01f;
    }
}

__global__ __launch_bounds__(256, 4) void k_fused(const float* __restrict__ q,
                                                  const float* __restrict__ k1,
                                                  const float* __restrict__ v1,
                                                  const float* __restrict__ v2,
                                                  const short* __restrict__ ws,
                                                  float* __restrict__ out) {
    __shared__ __align__(16) char smem[33856];
    const int bid  = blockIdx.x;
    const int role = bid % 3;           // 3 coprime with 8 XCDs -> uniform role spread
    const int sub  = bid / 3;           // 0..4095
    if (role == 0)      do_z(sub, q, ws, out, smem);
    else if (role == 1) do_score(sub, k1, ws, out, smem);
    else                do_vg(sub, v1, v2, out, smem);
}

extern "C" void kernel_launch(void* const* d_in, const int* in_sizes, int n_in,
                              void* d_out, int out_size, void* d_ws, size_t ws_size,
                              hipStream_t stream) {
    (void)in_sizes; (void)n_in; (void)ws_size; (void)out_size;
    const float* q  = (const float*)d_in[0];
    const float* k1 = (const float*)d_in[1];
    const float* k2 = (const float*)d_in[2];
    const float* v1 = (const float*)d_in[3];
    const float* v2 = (const float*)d_in[4];
    float* out = (float*)d_out;
    short* ws = (short*)d_ws;

    k_prep<<<dim3(256), dim3(256), 0, stream>>>(q, k1, k2, v1, v2, ws);
    k_fused<<<dim3(3 * BHN * TT), dim3(256), 0, stream>>>(q, k1, v1, v2, ws, out);
}